// Round 10
// baseline (438.605 us; speedup 1.0000x reference)
//
#include <hip/hip_runtime.h>
#include <stdint.h>

#define NU 100000
#define NI 200000
#define NT 300000          // NU + NI
#define D 64
#define NNZ 1200000
#define NHOPS 3
#define SL 4               // slices per row = NHOPS+1
#define ROWF (SL * D)      // 256 floats per output row
#define KS 8               // padded kept-edge slots per row
#define OVF_CAP 16384
#define NBIN 9             // degree bins 0..7, 8+

__host__ __device__ __forceinline__ uint32_t rotl32(uint32_t x, int r) {
    return (x << r) | (x >> (32 - r));
}

// Threefry-2x32, 20 rounds — matches jax._src.prng.threefry2x32
__host__ __device__ inline void tf2x32(uint32_t k0, uint32_t k1,
                                       uint32_t x0, uint32_t x1,
                                       uint32_t& o0, uint32_t& o1) {
    uint32_t ks0 = k0, ks1 = k1, ks2 = k0 ^ k1 ^ 0x1BD11BDAu;
    x0 += ks0; x1 += ks1;
#define RND(r) { x0 += x1; x1 = rotl32(x1, r); x1 ^= x0; }
    RND(13) RND(15) RND(26) RND(6)
    x0 += ks1; x1 += ks2 + 1u;
    RND(17) RND(29) RND(16) RND(24)
    x0 += ks2; x1 += ks0 + 2u;
    RND(13) RND(15) RND(26) RND(6)
    x0 += ks0; x1 += ks1 + 3u;
    RND(17) RND(29) RND(16) RND(24)
    x0 += ks1; x1 += ks2 + 4u;
    RND(13) RND(15) RND(26) RND(6)
    o0 = x0 + ks2; o1 = x1 + ks0 + 5u;
#undef RND
}

__device__ __forceinline__ uint32_t rbits(uint32_t k0, uint32_t k1, uint32_t j) {
    uint32_t o0, o1;
    tf2x32(k0, k1, 0u, j, o0, o1);
    return o0 ^ o1;
}

__device__ __forceinline__ float u01(uint32_t bits) {
    return __uint_as_float((bits >> 9) | 0x3f800000u) - 1.0f;
}

// keep edge  <=> u >= 0.5  <=> top bit of bits        (exact)
// keep mess  <=> u < 0.9f  <=> (bits>>9) < 7549747    (exact: 0.9f = 7549747/2^23)
#define MESS_KEEP_T 7549747u

// ------------------------- fast path -------------------------

__global__ void zero_kernel(int* __restrict__ p, int n) {
    int i = blockIdx.x * blockDim.x + threadIdx.x;
    if (i < n) p[i] = 0;
}

// per-hop scatter of KEPT edges into padded slots (R6-exact)
__global__ void scat_kernel(const int* __restrict__ rows,
                            const int* __restrict__ cols,
                            const float* __restrict__ vals,
                            int* __restrict__ kcnt,
                            int2* __restrict__ kslot,
                            int4* __restrict__ ovf,
                            uint32_t ke0, uint32_t ke1) {
    int e = blockIdx.x * blockDim.x + threadIdx.x;
    if (e >= NNZ) return;
    uint32_t b = rbits(ke0, ke1, (uint32_t)e);
    if (!(b & 0x80000000u)) return;
    int r = rows[e];
    int pos = atomicAdd(&kcnt[r], 1);
    if (pos < KS) {
        kslot[(size_t)r * KS + pos] = make_int2(cols[e], __float_as_int(vals[e] * 2.0f));
    } else {
        int oi = atomicAdd(&kcnt[NT], 1);
        if (oi < OVF_CAP) ovf[oi] = make_int4(r, cols[e], __float_as_int(vals[e] * 2.0f), 0);
    }
}

// bucket rows by kept-degree: order[b*NT + k] = row ids of bin b.
// bins counters live at kcnt[NT+1 .. NT+9].
__global__ void place_kernel(const int* __restrict__ kcnt,
                             int* __restrict__ bins,   // = kcnt + NT + 1
                             int* __restrict__ order) {
    __shared__ int lh[NBIN];
    __shared__ int lbase[NBIN];
    int tid = threadIdx.x;
    int r = blockIdx.x * blockDim.x + tid;
    if (tid < NBIN) lh[tid] = 0;
    __syncthreads();
    int b = 0, lp = 0;
    bool valid = (r < NT);
    if (valid) {
        int cnt = kcnt[r];
        b = (cnt < 8) ? cnt : 8;
        lp = atomicAdd(&lh[b], 1);
    }
    __syncthreads();
    if (tid < NBIN) lbase[tid] = (lh[tid] > 0) ? atomicAdd(&bins[tid], lh[tid]) : 0;
    __syncthreads();
    if (valid) order[(size_t)b * NT + lbase[b] + lp] = r;
}

// 8 same-degree rows per wave via order[]; lane = feature dim; mess-drop fused.
template <int H0>
__global__ void spmm9_kernel(const int* __restrict__ kcnt,
                             const int2* __restrict__ kslot,
                             const int4* __restrict__ ovf,
                             const int* __restrict__ order,
                             const float* __restrict__ ue,
                             const float* __restrict__ ie,
                             float* __restrict__ out, int hop,
                             uint32_t km0, uint32_t km1) {
    int w    = (blockIdx.x * blockDim.x + threadIdx.x) >> 6;
    int lane = threadIdx.x & 63;
    int g0   = w * 8;
    if (g0 >= NT) return;                       // NT % 8 == 0

    // ---- cumulative bin offsets (9 uniform cached loads) ----
    const int* bins = kcnt + NT + 1;
    int cum1, cum2, cum3, cum4, cum5, cum6, cum7, cum8, cum9;
    cum1 = bins[0];          cum2 = cum1 + bins[1];  cum3 = cum2 + bins[2];
    cum4 = cum3 + bins[3];   cum5 = cum4 + bins[4];  cum6 = cum5 + bins[5];
    cum7 = cum6 + bins[6];   cum8 = cum7 + bins[7];  cum9 = cum8 + bins[8];
    (void)cum9;

    // ---- my row (lanes 0..7) ----
    int myrow = 0;
    if (lane < 8) {
        int g = g0 + lane;
        int b = (g >= cum1) + (g >= cum2) + (g >= cum3) + (g >= cum4) +
                (g >= cum5) + (g >= cum6) + (g >= cum7) + (g >= cum8);
        int cb = 0;
        cb = (b > 0) ? cum1 : cb;  cb = (b > 1) ? cum2 : cb;
        cb = (b > 2) ? cum3 : cb;  cb = (b > 3) ? cum4 : cb;
        cb = (b > 4) ? cum5 : cb;  cb = (b > 5) ? cum6 : cb;
        cb = (b > 6) ? cum7 : cb;  cb = (b > 7) ? cum8 : cb;
        myrow = order[(size_t)b * NT + (g - cb)];
    }
    int mk = (lane < 8) ? kcnt[myrow] : 0;

    // rows broadcast to all lanes
    int row[8];
    #pragma unroll
    for (int r = 0; r < 8; ++r) row[r] = __shfl(myrow, r, 64);

    // ---- stage 1: slot load (row of my slot-group) ----
    int rr = row[lane >> 3];
    int2 kp = kslot[(size_t)rr * KS + (lane & 7)];

    int   cl = kp.x;
    float vl = __int_as_float(kp.y);

    int m[8];
    #pragma unroll
    for (int r = 0; r < 8; ++r) m[r] = __shfl(mk, r, 64);
    int mxf = 0;
    #pragma unroll
    for (int r = 0; r < 8; ++r) mxf = max(mxf, m[r]);
    int mx = (mxf < KS) ? mxf : KS;

    float acc[8] = {0.f, 0.f, 0.f, 0.f, 0.f, 0.f, 0.f, 0.f};

    // ---- gather loop: 8 independent 256B gathers per phase; phases = bin degree ----
    for (int j = 0; j < mx; ++j) {
        float vv[8]; int cc[8];
        #pragma unroll
        for (int r = 0; r < 8; ++r) {
            int slot = r * KS + j;
            float v = __shfl(vl, slot, 64);
            int   c = __shfl(cl, slot, 64);
            bool ok = (j < m[r]);               // guards 0xAA garbage in unused slots
            vv[r] = ok ? v : 0.0f;
            cc[r] = ok ? c : 0;                 // dropped -> hot row 0, cache-hit
        }
        float g[8];
        #pragma unroll
        for (int r = 0; r < 8; ++r) {
            if (H0) {
                const float* b = (cc[r] < NU) ? ue : ie;
                int c2 = (cc[r] < NU) ? cc[r] : cc[r] - NU;
                g[r] = b[(size_t)c2 * D + lane];
            } else {
                g[r] = out[(size_t)cc[r] * ROWF + (size_t)hop * D + lane];
            }
        }
        #pragma unroll
        for (int r = 0; r < 8; ++r) acc[r] += vv[r] * g[r];
    }

    // ---- cold overflow: rows with kept count > KS (~60/hop chip-wide, all in bin 8) ----
    if (mxf > KS) {
        int no = kcnt[NT];
        if (no > OVF_CAP) no = OVF_CAP;
        #pragma unroll
        for (int r = 0; r < 8; ++r) {           // static acc index
            if (m[r] > KS) {
                for (int i = 0; i < no; ++i) {
                    int4 ent = ovf[i];
                    if (ent.x == row[r]) {
                        float src;
                        if (H0) {
                            const float* b = (ent.y < NU) ? ue : ie;
                            int c2 = (ent.y < NU) ? ent.y : ent.y - NU;
                            src = b[(size_t)c2 * D + lane];
                        } else {
                            src = out[(size_t)ent.y * ROWF + (size_t)hop * D + lane];
                        }
                        acc[r] += __int_as_float(ent.z) * src;
                    }
                }
            }
        }
    }

    // ---- fused hop-0 slice-0 copy (per scattered row) ----
    if (H0) {
        #pragma unroll
        for (int r = 0; r < 8; ++r) {
            float e0 = (row[r] < NU) ? ue[(size_t)row[r] * D + lane]
                                     : ie[(size_t)(row[r] - NU) * D + lane];
            out[(size_t)row[r] * ROWF + lane] = e0;
        }
    }

    // ---- fused message dropout + store ----
    const float INVM = (float)(1.0 / (1.0 - 0.1));
    #pragma unroll
    for (int r = 0; r < 8; ++r) {
        uint32_t t = rbits(km0, km1, (uint32_t)(row[r] * D + lane)) >> 9;
        float a = (t < MESS_KEEP_T) ? acc[r] * INVM : 0.0f;
        out[(size_t)row[r] * ROWF + (size_t)(hop + 1) * D + lane] = a;
    }
}

// ------------------------- R1 small-ws fallback -------------------------

__global__ void init_kernel(const float4* __restrict__ ue,
                            const float4* __restrict__ ie,
                            float4* __restrict__ out) {
    int gid = blockIdx.x * blockDim.x + threadIdx.x;
    if (gid >= NT * 16) return;
    int n = gid >> 4, q = gid & 15;
    float4 v = (n < NU) ? ue[n * 16 + q] : ie[(n - NU) * 16 + q];
    float4 z = make_float4(0.f, 0.f, 0.f, 0.f);
    float4* row = out + (size_t)n * 64;
    row[q]      = v;
    row[16 + q] = z;
    row[32 + q] = z;
    row[48 + q] = z;
}

__global__ void spmm_inline_kernel(const float* __restrict__ vals,
                                   const int* __restrict__ rows,
                                   const int* __restrict__ cols,
                                   float* __restrict__ out, int hop,
                                   uint32_t ke0, uint32_t ke1) {
    int wid  = (blockIdx.x * blockDim.x + threadIdx.x) >> 6;
    int lane = threadIdx.x & 63;
    if (wid >= NNZ) return;
    uint32_t b = rbits(ke0, ke1, (uint32_t)wid);
    if (!(b & 0x80000000u)) return;
    float ve = vals[wid] * 2.0f;
    int r = rows[wid], c = cols[wid];
    float x = out[c * ROWF + hop * D + lane];
    unsafeAtomicAdd(&out[r * ROWF + (hop + 1) * D + lane], ve * x);
}

__global__ void mess_drop_kernel(float* __restrict__ out, int hop,
                                 uint32_t km0, uint32_t km1) {
    int j = blockIdx.x * blockDim.x + threadIdx.x;
    if (j >= NT * D) return;
    uint32_t t = rbits(km0, km1, (uint32_t)j) >> 9;
    int n = j >> 6, d = j & 63;
    int idx = n * ROWF + (hop + 1) * D + d;
    const float INVM = (float)(1.0 / (1.0 - 0.1));
    float a = out[idx];
    out[idx] = (t < MESS_KEEP_T) ? a * INVM : 0.0f;
}

// ------------------------- launch -------------------------

extern "C" void kernel_launch(void* const* d_in, const int* in_sizes, int n_in,
                              void* d_out, int out_size, void* d_ws, size_t ws_size,
                              hipStream_t stream) {
    const float* ue   = (const float*)d_in[0];
    const float* ie   = (const float*)d_in[1];
    const float* vals = (const float*)d_in[2];
    const int*   rows = (const int*)d_in[3];
    const int*   cols = (const int*)d_in[4];
    float* out = (float*)d_out;

    // ws layout: kcnt (NT+16 ints: [NT]=ovf ctr, [NT+1..NT+9]=bins) | kslot | ovf | order
    const size_t off_kcnt  = 0;
    const size_t off_kslot = ((size_t)(NT + 16) * 4 + 15) & ~(size_t)15;     // 1,200,064
    const size_t off_kovf  = off_kslot + (size_t)NT * KS * 8;                // +19.2 MB
    const size_t off_order = off_kovf + (size_t)OVF_CAP * 16;                // +0.26 MB
    const size_t need      = off_order + (size_t)NBIN * NT * 4;              // +10.8 MB ~= 31.7 MB

    uint32_t kf0, kf1;
    uint32_t ke0[NHOPS], ke1[NHOPS], km0[NHOPS], km1[NHOPS];
    for (int h = 0; h < NHOPS; ++h) {
        tf2x32(0u, 42u, 0u, (uint32_t)h, kf0, kf1);
        tf2x32(kf0, kf1, 0u, 0u, ke0[h], ke1[h]);
        tf2x32(kf0, kf1, 0u, 1u, km0[h], km1[h]);
    }

    const int spmm_grid = (NT / 8 * 64 + 255) / 256;   // 9375 blocks

    if (ws_size >= need) {
        int*  kcnt  = (int*)((char*)d_ws + off_kcnt);
        int2* kslot = (int2*)((char*)d_ws + off_kslot);
        int4* kovf  = (int4*)((char*)d_ws + off_kovf);
        int*  order = (int*)((char*)d_ws + off_order);

        for (int h = 0; h < NHOPS; ++h) {
            zero_kernel<<<(NT + 16 + 255) / 256, 256, 0, stream>>>(kcnt, NT + 16);
            scat_kernel<<<(NNZ + 255) / 256, 256, 0, stream>>>(
                rows, cols, vals, kcnt, kslot, kovf, ke0[h], ke1[h]);
            place_kernel<<<(NT + 255) / 256, 256, 0, stream>>>(
                kcnt, kcnt + NT + 1, order);
            if (h == 0)
                spmm9_kernel<1><<<spmm_grid, 256, 0, stream>>>(
                    kcnt, kslot, kovf, order, ue, ie, out, h, km0[h], km1[h]);
            else
                spmm9_kernel<0><<<spmm_grid, 256, 0, stream>>>(
                    kcnt, kslot, kovf, order, ue, ie, out, h, km0[h], km1[h]);
        }
    } else {
        init_kernel<<<(NT * 16 + 255) / 256, 256, 0, stream>>>(
            (const float4*)ue, (const float4*)ie, (float4*)out);
        for (int h = 0; h < NHOPS; ++h) {
            spmm_inline_kernel<<<(NNZ + 3) / 4, 256, 0, stream>>>(
                vals, rows, cols, out, h, ke0[h], ke1[h]);
            mess_drop_kernel<<<(NT * D + 255) / 256, 256, 0, stream>>>(out, h, km0[h], km1[h]);
        }
    }
}

// Round 11
// 360.838 us; speedup vs baseline: 1.2155x; 1.2155x over previous
//
#include <hip/hip_runtime.h>
#include <stdint.h>

#define NU 100000
#define NI 200000
#define NT 300000          // NU + NI
#define D 64
#define NNZ 1200000
#define NHOPS 3
#define SL 4               // slices per row = NHOPS+1
#define ROWF (SL * D)      // 256 floats per output row
#define KS 8               // padded kept-edge slots per row
#define OVF_CAP 16384

__host__ __device__ __forceinline__ uint32_t rotl32(uint32_t x, int r) {
    return (x << r) | (x >> (32 - r));
}

// Threefry-2x32, 20 rounds — matches jax._src.prng.threefry2x32
__host__ __device__ inline void tf2x32(uint32_t k0, uint32_t k1,
                                       uint32_t x0, uint32_t x1,
                                       uint32_t& o0, uint32_t& o1) {
    uint32_t ks0 = k0, ks1 = k1, ks2 = k0 ^ k1 ^ 0x1BD11BDAu;
    x0 += ks0; x1 += ks1;
#define RND(r) { x0 += x1; x1 = rotl32(x1, r); x1 ^= x0; }
    RND(13) RND(15) RND(26) RND(6)
    x0 += ks1; x1 += ks2 + 1u;
    RND(17) RND(29) RND(16) RND(24)
    x0 += ks2; x1 += ks0 + 2u;
    RND(13) RND(15) RND(26) RND(6)
    x0 += ks0; x1 += ks1 + 3u;
    RND(17) RND(29) RND(16) RND(24)
    x0 += ks1; x1 += ks2 + 4u;
    RND(13) RND(15) RND(26) RND(6)
    o0 = x0 + ks2; o1 = x1 + ks0 + 5u;
#undef RND
}

__device__ __forceinline__ uint32_t rbits(uint32_t k0, uint32_t k1, uint32_t j) {
    uint32_t o0, o1;
    tf2x32(k0, k1, 0u, j, o0, o1);
    return o0 ^ o1;
}

__device__ __forceinline__ float u01(uint32_t bits) {
    return __uint_as_float((bits >> 9) | 0x3f800000u) - 1.0f;
}

// keep edge  <=> u >= 0.5  <=> top bit of bits        (exact)
// keep mess  <=> u < 0.9f  <=> (bits>>9) < 7549747    (exact: 0.9f = 7549747/2^23)
#define MESS_KEEP_T 7549747u

// ------------------------- fast path (R6-exact kernels) -------------------------

// per-hop scatter of KEPT edges into padded slots
__global__ void scat_kernel(const int* __restrict__ rows,
                            const int* __restrict__ cols,
                            const float* __restrict__ vals,
                            int* __restrict__ kcnt,
                            int2* __restrict__ kslot,
                            int4* __restrict__ ovf,
                            uint32_t ke0, uint32_t ke1) {
    int e = blockIdx.x * blockDim.x + threadIdx.x;
    if (e >= NNZ) return;
    uint32_t b = rbits(ke0, ke1, (uint32_t)e);
    if (!(b & 0x80000000u)) return;
    int r = rows[e];
    int pos = atomicAdd(&kcnt[r], 1);
    if (pos < KS) {
        kslot[(size_t)r * KS + pos] = make_int2(cols[e], __float_as_int(vals[e] * 2.0f));
    } else {
        int oi = atomicAdd(&kcnt[NT], 1);
        if (oi < OVF_CAP) ovf[oi] = make_int4(r, cols[e], __float_as_int(vals[e] * 2.0f), 0);
    }
}

// 8 rows per wave; lane = feature dim; mess-drop fused; H0 fuses slice-0 copy
template <int H0>
__global__ void spmm8_kernel(const int* __restrict__ kcnt,
                             const int2* __restrict__ kslot,
                             const int4* __restrict__ ovf,
                             const float* __restrict__ ue,
                             const float* __restrict__ ie,
                             float* __restrict__ out, int hop,
                             uint32_t km0, uint32_t km1) {
    int w    = (blockIdx.x * blockDim.x + threadIdx.x) >> 6;
    int lane = threadIdx.x & 63;
    int r0   = w * 8;
    if (r0 >= NT) return;                       // NT % 8 == 0

    // ---- stage 1: independent loads, issued together ----
    int mk = 0;
    if (lane < 8) mk = kcnt[r0 + lane];
    int2 kp = kslot[(size_t)r0 * KS + lane];    // 8 rows x 8 slots = 1 int2/lane

    float4 e04a, e04b;
    if (H0) {
        // NU % 8 == 0 -> all 8 rows on one side of the user/item split
        const float4* s4 = (r0 < NU) ? (const float4*)(ue + (size_t)r0 * D)
                                     : (const float4*)(ie + (size_t)(r0 - NU) * D);
        e04a = s4[lane];
        e04b = s4[lane + 64];
    }

    int   cl = kp.x;
    float vl = __int_as_float(kp.y);

    int m[8];
    #pragma unroll
    for (int r = 0; r < 8; ++r) m[r] = __shfl(mk, r, 64);
    int mxf = 0;
    #pragma unroll
    for (int r = 0; r < 8; ++r) mxf = max(mxf, m[r]);
    int mx = (mxf < KS) ? mxf : KS;

    float acc[8] = {0.f, 0.f, 0.f, 0.f, 0.f, 0.f, 0.f, 0.f};

    // ---- gather loop: 8 independent 256B gathers per phase ----
    for (int j = 0; j < mx; ++j) {
        float vv[8]; int cc[8];
        #pragma unroll
        for (int r = 0; r < 8; ++r) {
            int slot = r * KS + j;
            float v = __shfl(vl, slot, 64);
            int   c = __shfl(cl, slot, 64);
            bool ok = (j < m[r]);               // guards 0xAA garbage in unused slots
            vv[r] = ok ? v : 0.0f;
            cc[r] = ok ? c : 0;                 // dropped -> hot row 0, cache-hit
        }
        float g[8];
        #pragma unroll
        for (int r = 0; r < 8; ++r) {
            if (H0) {
                const float* b = (cc[r] < NU) ? ue : ie;
                int c2 = (cc[r] < NU) ? cc[r] : cc[r] - NU;
                g[r] = b[(size_t)c2 * D + lane];
            } else {
                g[r] = out[(size_t)cc[r] * ROWF + (size_t)hop * D + lane];
            }
        }
        #pragma unroll
        for (int r = 0; r < 8; ++r) acc[r] += vv[r] * g[r];
    }

    // ---- cold overflow: rows with kept count > KS (~60/hop chip-wide) ----
    if (mxf > KS) {
        int no = kcnt[NT];
        if (no > OVF_CAP) no = OVF_CAP;
        #pragma unroll
        for (int r = 0; r < 8; ++r) {           // static acc index
            if (m[r] > KS) {
                for (int i = 0; i < no; ++i) {
                    int4 ent = ovf[i];
                    if (ent.x == r0 + r) {
                        float src;
                        if (H0) {
                            const float* b = (ent.y < NU) ? ue : ie;
                            int c2 = (ent.y < NU) ? ent.y : ent.y - NU;
                            src = b[(size_t)c2 * D + lane];
                        } else {
                            src = out[(size_t)ent.y * ROWF + (size_t)hop * D + lane];
                        }
                        acc[r] += __int_as_float(ent.z) * src;
                    }
                }
            }
        }
    }

    // ---- fused hop-0 slice-0 copy ----
    if (H0) {
        int f0 = lane, f1 = lane + 64;
        ((float4*)out)[(size_t)(r0 + (f0 >> 4)) * 64 + (f0 & 15)] = e04a;
        ((float4*)out)[(size_t)(r0 + (f1 >> 4)) * 64 + (f1 & 15)] = e04b;
    }

    // ---- fused message dropout + store ----
    const float INVM = (float)(1.0 / (1.0 - 0.1));
    #pragma unroll
    for (int r = 0; r < 8; ++r) {
        uint32_t t = rbits(km0, km1, (uint32_t)((r0 + r) * D + lane)) >> 9;
        float a = (t < MESS_KEEP_T) ? acc[r] * INVM : 0.0f;
        out[(size_t)(r0 + r) * ROWF + (size_t)(hop + 1) * D + lane] = a;
    }
}

// ------------------------- R1 small-ws fallback -------------------------

__global__ void init_kernel(const float4* __restrict__ ue,
                            const float4* __restrict__ ie,
                            float4* __restrict__ out) {
    int gid = blockIdx.x * blockDim.x + threadIdx.x;
    if (gid >= NT * 16) return;
    int n = gid >> 4, q = gid & 15;
    float4 v = (n < NU) ? ue[n * 16 + q] : ie[(n - NU) * 16 + q];
    float4 z = make_float4(0.f, 0.f, 0.f, 0.f);
    float4* row = out + (size_t)n * 64;
    row[q]      = v;
    row[16 + q] = z;
    row[32 + q] = z;
    row[48 + q] = z;
}

__global__ void spmm_inline_kernel(const float* __restrict__ vals,
                                   const int* __restrict__ rows,
                                   const int* __restrict__ cols,
                                   float* __restrict__ out, int hop,
                                   uint32_t ke0, uint32_t ke1) {
    int wid  = (blockIdx.x * blockDim.x + threadIdx.x) >> 6;
    int lane = threadIdx.x & 63;
    if (wid >= NNZ) return;
    uint32_t b = rbits(ke0, ke1, (uint32_t)wid);
    if (!(b & 0x80000000u)) return;
    float ve = vals[wid] * 2.0f;
    int r = rows[wid], c = cols[wid];
    float x = out[c * ROWF + hop * D + lane];
    unsafeAtomicAdd(&out[r * ROWF + (hop + 1) * D + lane], ve * x);
}

__global__ void mess_drop_kernel(float* __restrict__ out, int hop,
                                 uint32_t km0, uint32_t km1) {
    int j = blockIdx.x * blockDim.x + threadIdx.x;
    if (j >= NT * D) return;
    uint32_t t = rbits(km0, km1, (uint32_t)j) >> 9;
    int n = j >> 6, d = j & 63;
    int idx = n * ROWF + (hop + 1) * D + d;
    const float INVM = (float)(1.0 / (1.0 - 0.1));
    float a = out[idx];
    out[idx] = (t < MESS_KEEP_T) ? a * INVM : 0.0f;
}

// ------------------------- launch -------------------------

extern "C" void kernel_launch(void* const* d_in, const int* in_sizes, int n_in,
                              void* d_out, int out_size, void* d_ws, size_t ws_size,
                              hipStream_t stream) {
    const float* ue   = (const float*)d_in[0];
    const float* ie   = (const float*)d_in[1];
    const float* vals = (const float*)d_in[2];
    const int*   rows = (const int*)d_in[3];
    const int*   cols = (const int*)d_in[4];
    float* out = (float*)d_out;

    // ws layout: 3 contiguous per-hop counter arrays, then 3 kslot, then 3 ovf.
    // Counters zeroed in ONE upfront memset; per-hop kernels touch only their
    // own 19.2 MB working set (R6 behavior, minus the per-hop zero dispatches).
    const size_t off_kcnt3  = 0;                                    // 3*(NT+1)*4 B
    const size_t off_kslot3 = ((size_t)3 * (NT + 1) * 4 + 15) & ~(size_t)15;
    const size_t off_ovf3   = off_kslot3 + (size_t)3 * NT * KS * 8;
    const size_t need_fast  = off_ovf3 + (size_t)3 * OVF_CAP * 16;  // ~61.3 MB

    // mid path (single-hop buffers + per-hop zero) ~20.7 MB
    const size_t off_kcnt  = 0;
    const size_t off_kslot = 1200016;
    const size_t off_kovf  = off_kslot + (size_t)NT * KS * 8;
    const size_t need_mid  = off_kovf + (size_t)OVF_CAP * 16;

    uint32_t kf0, kf1;
    uint32_t ke0[NHOPS], ke1[NHOPS], km0[NHOPS], km1[NHOPS];
    for (int h = 0; h < NHOPS; ++h) {
        tf2x32(0u, 42u, 0u, (uint32_t)h, kf0, kf1);
        tf2x32(kf0, kf1, 0u, 0u, ke0[h], ke1[h]);
        tf2x32(kf0, kf1, 0u, 1u, km0[h], km1[h]);
    }

    const int spmm_grid = (NT / 8 * 64 + 255) / 256;   // 9375 blocks

    if (ws_size >= need_fast) {
        int*  kcnt3  = (int*)((char*)d_ws + off_kcnt3);
        int2* kslot3 = (int2*)((char*)d_ws + off_kslot3);
        int4* ovf3   = (int4*)((char*)d_ws + off_ovf3);

        hipMemsetAsync(kcnt3, 0, (size_t)3 * (NT + 1) * sizeof(int), stream);

        for (int h = 0; h < NHOPS; ++h) {
            int*  kc = kcnt3 + h * (NT + 1);
            int2* ks = kslot3 + (size_t)h * NT * KS;
            int4* ov = ovf3 + (size_t)h * OVF_CAP;
            scat_kernel<<<(NNZ + 255) / 256, 256, 0, stream>>>(
                rows, cols, vals, kc, ks, ov, ke0[h], ke1[h]);
            if (h == 0)
                spmm8_kernel<1><<<spmm_grid, 256, 0, stream>>>(
                    kc, ks, ov, ue, ie, out, h, km0[h], km1[h]);
            else
                spmm8_kernel<0><<<spmm_grid, 256, 0, stream>>>(
                    kc, ks, ov, ue, ie, out, h, km0[h], km1[h]);
        }
    } else if (ws_size >= need_mid) {
        int*  kcnt  = (int*)((char*)d_ws + off_kcnt);
        int2* kslot = (int2*)((char*)d_ws + off_kslot);
        int4* kovf  = (int4*)((char*)d_ws + off_kovf);

        for (int h = 0; h < NHOPS; ++h) {
            hipMemsetAsync(kcnt, 0, (NT + 1) * sizeof(int), stream);
            scat_kernel<<<(NNZ + 255) / 256, 256, 0, stream>>>(
                rows, cols, vals, kcnt, kslot, kovf, ke0[h], ke1[h]);
            if (h == 0)
                spmm8_kernel<1><<<spmm_grid, 256, 0, stream>>>(
                    kcnt, kslot, kovf, ue, ie, out, h, km0[h], km1[h]);
            else
                spmm8_kernel<0><<<spmm_grid, 256, 0, stream>>>(
                    kcnt, kslot, kovf, ue, ie, out, h, km0[h], km1[h]);
        }
    } else {
        init_kernel<<<(NT * 16 + 255) / 256, 256, 0, stream>>>(
            (const float4*)ue, (const float4*)ie, (float4*)out);
        for (int h = 0; h < NHOPS; ++h) {
            spmm_inline_kernel<<<(NNZ + 3) / 4, 256, 0, stream>>>(
                vals, rows, cols, out, h, ke0[h], ke1[h]);
            mess_drop_kernel<<<(NT * D + 255) / 256, 256, 0, stream>>>(out, h, km0[h], km1[h]);
        }
    }
}

// Round 12
// 345.438 us; speedup vs baseline: 1.2697x; 1.0446x over previous
//
#include <hip/hip_runtime.h>
#include <stdint.h>

#define NU 100000
#define NI 200000
#define NT 300000          // NU + NI
#define D 64
#define NNZ 1200000
#define NHOPS 3
#define SL 4               // slices per row = NHOPS+1
#define ROWF (SL * D)      // 256 floats per output row
#define KS 8               // padded kept-edge slots per row
#define OVF_CAP 16384      // overflow entries (rows with >KS kept edges)

__host__ __device__ __forceinline__ uint32_t rotl32(uint32_t x, int r) {
    return (x << r) | (x >> (32 - r));
}

// Threefry-2x32, 20 rounds — matches jax._src.prng.threefry2x32
__host__ __device__ inline void tf2x32(uint32_t k0, uint32_t k1,
                                       uint32_t x0, uint32_t x1,
                                       uint32_t& o0, uint32_t& o1) {
    uint32_t ks0 = k0, ks1 = k1, ks2 = k0 ^ k1 ^ 0x1BD11BDAu;
    x0 += ks0; x1 += ks1;
#define RND(r) { x0 += x1; x1 = rotl32(x1, r); x1 ^= x0; }
    RND(13) RND(15) RND(26) RND(6)
    x0 += ks1; x1 += ks2 + 1u;
    RND(17) RND(29) RND(16) RND(24)
    x0 += ks2; x1 += ks0 + 2u;
    RND(13) RND(15) RND(26) RND(6)
    x0 += ks0; x1 += ks1 + 3u;
    RND(17) RND(29) RND(16) RND(24)
    x0 += ks1; x1 += ks2 + 4u;
    RND(13) RND(15) RND(26) RND(6)
    o0 = x0 + ks2; o1 = x1 + ks0 + 5u;
#undef RND
}

__device__ __forceinline__ uint32_t rbits(uint32_t k0, uint32_t k1, uint32_t j) {
    uint32_t o0, o1;
    tf2x32(k0, k1, 0u, j, o0, o1);
    return o0 ^ o1;
}

__device__ __forceinline__ float u01(uint32_t bits) {
    return __uint_as_float((bits >> 9) | 0x3f800000u) - 1.0f;
}

// ------------------------- fast path -------------------------

__global__ void zero_kernel(int* __restrict__ p, int n) {
    int i = blockIdx.x * blockDim.x + threadIdx.x;
    if (i < n) p[i] = 0;
}

// per-hop direct scatter of KEPT edges into padded slots.
// kcnt[NT] doubles as the overflow counter.
__global__ void scat_kernel(const int* __restrict__ rows,
                            const int* __restrict__ cols,
                            const float* __restrict__ vals,
                            int* __restrict__ kcnt,
                            int2* __restrict__ kslot,
                            int4* __restrict__ ovf,
                            uint32_t ke0, uint32_t ke1) {
    int e = blockIdx.x * blockDim.x + threadIdx.x;
    if (e >= NNZ) return;
    float u = u01(rbits(ke0, ke1, (uint32_t)e));
    if (u < 0.5f) return;                       // dropped edge
    int r = rows[e];
    int c = cols[e];
    float v2 = vals[e] * 2.0f;                  // 1/(1-0.5) scale, exact
    int pos = atomicAdd(&kcnt[r], 1);
    if (pos < KS) {
        kslot[(size_t)r * KS + pos] = make_int2(c, __float_as_int(v2));
    } else {
        int oi = atomicAdd(&kcnt[NT], 1);
        if (oi < OVF_CAP) ovf[oi] = make_int4(r, c, __float_as_int(v2), 0);
    }
}

// 8 rows per wave; lane = feature dim; mess-drop fused; H0 fuses slice-0 copy
template <int H0>
__global__ void spmm8_kernel(const int* __restrict__ kcnt,
                             const int2* __restrict__ kslot,
                             const int4* __restrict__ ovf,
                             const float* __restrict__ ue,
                             const float* __restrict__ ie,
                             float* __restrict__ out, int hop,
                             uint32_t km0, uint32_t km1) {
    int w    = (blockIdx.x * blockDim.x + threadIdx.x) >> 6;
    int lane = threadIdx.x & 63;
    int r0   = w * 8;
    if (r0 >= NT) return;                       // NT % 8 == 0

    // ---- stage 1: independent loads, issued together ----
    int mk = 0;
    if (lane < 8) mk = kcnt[r0 + lane];
    int2 kp = kslot[(size_t)r0 * KS + lane];    // 8 rows x 8 slots = 64 = 1/lane

    float4 e04a, e04b;
    if (H0) {
        // NU % 8 == 0 → all 8 rows on the same side of the user/item split
        const float4* s4 = (r0 < NU) ? (const float4*)(ue + (size_t)r0 * D)
                                     : (const float4*)(ie + (size_t)(r0 - NU) * D);
        e04a = s4[lane];
        e04b = s4[lane + 64];
    }

    int   cl = kp.x;
    float vl = __int_as_float(kp.y);

    int m[8];
    #pragma unroll
    for (int r = 0; r < 8; ++r) m[r] = __shfl(mk, r, 64);
    int mxf = 0;
    #pragma unroll
    for (int r = 0; r < 8; ++r) mxf = max(mxf, m[r]);
    int mx = (mxf < KS) ? mxf : KS;

    float acc[8] = {0.f, 0.f, 0.f, 0.f, 0.f, 0.f, 0.f, 0.f};

    // ---- stage 2: gathers, 8 independent per iteration ----
    for (int j = 0; j < mx; ++j) {
        float vv[8]; int cc[8];
        #pragma unroll
        for (int r = 0; r < 8; ++r) {
            int slot = r * KS + j;
            float v = __shfl(vl, slot, 64);
            int   c = __shfl(cl, slot, 64);
            bool ok = (j < m[r]);               // guards 0xAA garbage in unused slots
            vv[r] = ok ? v : 0.0f;
            cc[r] = ok ? c : 0;
        }
        float g[8];
        #pragma unroll
        for (int r = 0; r < 8; ++r) {
            if (H0) {
                const float* b = (cc[r] < NU) ? ue : ie;
                int c2 = (cc[r] < NU) ? cc[r] : cc[r] - NU;
                g[r] = b[(size_t)c2 * D + lane];
            } else {
                g[r] = out[(size_t)cc[r] * ROWF + (size_t)hop * D + lane];
            }
        }
        #pragma unroll
        for (int r = 0; r < 8; ++r) acc[r] += vv[r] * g[r];
    }

    // ---- cold overflow: rows with kept count > KS (expected ~60/hop chip-wide) ----
    if (mxf > KS) {
        int no = kcnt[NT];
        if (no > OVF_CAP) no = OVF_CAP;
        #pragma unroll
        for (int r = 0; r < 8; ++r) {           // static acc index (rule #20)
            if (m[r] > KS) {
                for (int i = 0; i < no; ++i) {
                    int4 ent = ovf[i];
                    if (ent.x == r0 + r) {
                        float src;
                        if (H0) {
                            const float* b = (ent.y < NU) ? ue : ie;
                            int c2 = (ent.y < NU) ? ent.y : ent.y - NU;
                            src = b[(size_t)c2 * D + lane];
                        } else {
                            src = out[(size_t)ent.y * ROWF + (size_t)hop * D + lane];
                        }
                        acc[r] += __int_as_float(ent.z) * src;
                    }
                }
            }
        }
    }

    // ---- fused hop-0 slice-0 copy ----
    if (H0) {
        int f0 = lane, f1 = lane + 64;
        ((float4*)out)[(size_t)(r0 + (f0 >> 4)) * 64 + (f0 & 15)] = e04a;
        ((float4*)out)[(size_t)(r0 + (f1 >> 4)) * 64 + (f1 & 15)] = e04b;
    }

    // ---- fused message dropout + store ----
    const float P_KEEP = (float)(1.0 - 0.1);
    const float INVM   = (float)(1.0 / (1.0 - 0.1));
    #pragma unroll
    for (int r = 0; r < 8; ++r) {
        float um = u01(rbits(km0, km1, (uint32_t)((r0 + r) * D + lane)));
        float a  = (um < P_KEEP) ? acc[r] * INVM : 0.0f;
        out[(size_t)(r0 + r) * ROWF + (size_t)(hop + 1) * D + lane] = a;
    }
}

// ------------------------- R1 small-ws fallback -------------------------

__global__ void init_kernel(const float4* __restrict__ ue,
                            const float4* __restrict__ ie,
                            float4* __restrict__ out) {
    int gid = blockIdx.x * blockDim.x + threadIdx.x;
    if (gid >= NT * 16) return;
    int n = gid >> 4, q = gid & 15;
    float4 v = (n < NU) ? ue[n * 16 + q] : ie[(n - NU) * 16 + q];
    float4 z = make_float4(0.f, 0.f, 0.f, 0.f);
    float4* row = out + (size_t)n * 64;
    row[q]      = v;
    row[16 + q] = z;
    row[32 + q] = z;
    row[48 + q] = z;
}

__global__ void spmm_inline_kernel(const float* __restrict__ vals,
                                   const int* __restrict__ rows,
                                   const int* __restrict__ cols,
                                   float* __restrict__ out, int hop,
                                   uint32_t ke0, uint32_t ke1) {
    int wid  = (blockIdx.x * blockDim.x + threadIdx.x) >> 6;
    int lane = threadIdx.x & 63;
    if (wid >= NNZ) return;
    float u = u01(rbits(ke0, ke1, (uint32_t)wid));
    if (u < 0.5f) return;
    float ve = vals[wid] * 2.0f;
    int r = rows[wid], c = cols[wid];
    float x = out[c * ROWF + hop * D + lane];
    unsafeAtomicAdd(&out[r * ROWF + (hop + 1) * D + lane], ve * x);
}

__global__ void mess_drop_kernel(float* __restrict__ out, int hop,
                                 uint32_t km0, uint32_t km1) {
    int j = blockIdx.x * blockDim.x + threadIdx.x;
    if (j >= NT * D) return;
    float u = u01(rbits(km0, km1, (uint32_t)j));
    int n = j >> 6, d = j & 63;
    int idx = n * ROWF + (hop + 1) * D + d;
    const float P_KEEP = (float)(1.0 - 0.1);
    const float INVM   = (float)(1.0 / (1.0 - 0.1));
    float a = out[idx];
    out[idx] = (u < P_KEEP) ? a * INVM : 0.0f;
}

// ------------------------- launch -------------------------

extern "C" void kernel_launch(void* const* d_in, const int* in_sizes, int n_in,
                              void* d_out, int out_size, void* d_ws, size_t ws_size,
                              hipStream_t stream) {
    const float* ue   = (const float*)d_in[0];
    const float* ie   = (const float*)d_in[1];
    const float* vals = (const float*)d_in[2];
    const int*   rows = (const int*)d_in[3];
    const int*   cols = (const int*)d_in[4];
    float* out = (float*)d_out;

    // ws layout (fast path): kcnt (NT+1 ints) | kslot (NT*KS int2) | ovf (int4)
    const size_t off_kcnt  = 0;
    const size_t off_kslot = 1200016;                              // 16B aligned
    const size_t off_ovf   = off_kslot + (size_t)NT * KS * 8;      // 20,400,016
    const size_t need      = off_ovf + (size_t)OVF_CAP * 16;       // 20,662,160

    uint32_t kf0, kf1;
    uint32_t ke0[NHOPS], ke1[NHOPS], km0[NHOPS], km1[NHOPS];
    for (int h = 0; h < NHOPS; ++h) {
        tf2x32(0u, 42u, 0u, (uint32_t)h, kf0, kf1);
        tf2x32(kf0, kf1, 0u, 0u, ke0[h], ke1[h]);
        tf2x32(kf0, kf1, 0u, 1u, km0[h], km1[h]);
    }

    if (ws_size >= need) {
        int*  kcnt  = (int*)((char*)d_ws + off_kcnt);
        int2* kslot = (int2*)((char*)d_ws + off_kslot);
        int4* ovf   = (int4*)((char*)d_ws + off_ovf);

        for (int h = 0; h < NHOPS; ++h) {
            zero_kernel<<<(NT + 1 + 255) / 256, 256, 0, stream>>>(kcnt, NT + 1);
            scat_kernel<<<(NNZ + 255) / 256, 256, 0, stream>>>(
                rows, cols, vals, kcnt, kslot, ovf, ke0[h], ke1[h]);
            if (h == 0)
                spmm8_kernel<1><<<(NT / 8 * 64 + 255) / 256, 256, 0, stream>>>(
                    kcnt, kslot, ovf, ue, ie, out, h, km0[h], km1[h]);
            else
                spmm8_kernel<0><<<(NT / 8 * 64 + 255) / 256, 256, 0, stream>>>(
                    kcnt, kslot, ovf, ue, ie, out, h, km0[h], km1[h]);
        }
    } else {
        init_kernel<<<(NT * 16 + 255) / 256, 256, 0, stream>>>(
            (const float4*)ue, (const float4*)ie, (float4*)out);
        for (int h = 0; h < NHOPS; ++h) {
            spmm_inline_kernel<<<(NNZ + 3) / 4, 256, 0, stream>>>(
                vals, rows, cols, out, h, ke0[h], ke1[h]);
            mess_drop_kernel<<<(NT * D + 255) / 256, 256, 0, stream>>>(out, h, km0[h], km1[h]);
        }
    }
}